// Round 1
// baseline (648.616 us; speedup 1.0000x reference)
//
#include <hip/hip_runtime.h>

typedef __attribute__((ext_vector_type(4))) float f32x4;
typedef __attribute__((ext_vector_type(8))) short bf16x8;
typedef __attribute__((ext_vector_type(8))) unsigned short u16x8;

__device__ __forceinline__ unsigned short f2bf(float f) {
  unsigned int u = __float_as_uint(f);
  u += 0x7FFFu + ((u >> 16) & 1u);
  return (unsigned short)(u >> 16);
}
__device__ __forceinline__ float bf2f(unsigned short s) {
  return __uint_as_float(((unsigned int)s) << 16);
}

__device__ __forceinline__ void gll16(const void* g, void* l) {
  __builtin_amdgcn_global_load_lds((const __attribute__((address_space(1))) void*)g,
                                   (__attribute__((address_space(3))) void*)l, 16, 0, 0);
}

// ---------------- x (fp32) -> bf16 ----------------
__global__ __launch_bounds__(256) void cvt_f32_bf16(const float* __restrict__ in,
                                                    unsigned short* __restrict__ out,
                                                    int n8) {
  int i = blockIdx.x * blockDim.x + threadIdx.x;
  int stride = gridDim.x * blockDim.x;
  for (; i < n8; i += stride) {
    const float4* p = (const float4*)in + (size_t)i * 2;
    float4 a = p[0], b = p[1];
    u16x8 r;
    r[0] = f2bf(a.x); r[1] = f2bf(a.y); r[2] = f2bf(a.z); r[3] = f2bf(a.w);
    r[4] = f2bf(b.x); r[5] = f2bf(b.y); r[6] = f2bf(b.z); r[7] = f2bf(b.w);
    *(u16x8*)(out + (size_t)i * 8) = r;
  }
}

// ---------------- W [K][N] fp32 -> Wt [N][K] bf16 ----------------
__global__ __launch_bounds__(1024) void wtrans(const float* __restrict__ W,
                                               unsigned short* __restrict__ Wt) {
  __shared__ float t[32][33];
  const int k0 = blockIdx.x * 32, n0 = blockIdx.y * 32;
  t[threadIdx.y][threadIdx.x] = W[(size_t)(k0 + threadIdx.y) * 512 + n0 + threadIdx.x];
  __syncthreads();
  Wt[(size_t)(n0 + threadIdx.y) * 512 + k0 + threadIdx.x] = f2bf(t[threadIdx.x][threadIdx.y]);
}

// ---------------- GEMM: C[M=81920][512] = A[.][512](bf16) * W  (+bias) ----------------
// Bt is W^T stored [N=512][K=512] bf16 row-major.
// 128x128 tile, BK=64, 4 waves (2x2), 16x16x32 MFMA, XOR-8 LDS swizzle,
// linear global_load_lds dest + pre-swizzled global source (rule #21).
template <typename OutT>
__global__ __launch_bounds__(256) void gemm_bt(const unsigned short* __restrict__ A,
                                               const unsigned short* __restrict__ Bt,
                                               const float* __restrict__ bias,
                                               OutT* __restrict__ C) {
  __shared__ unsigned short As[128 * 64];
  __shared__ unsigned short Bs[128 * 64];

  const int tid = threadIdx.x;
  const int lane = tid & 63;
  const int wid = tid >> 6;
  const int wr = wid >> 1;  // wave row 0..1
  const int wc = wid & 1;   // wave col 0..1
  const int u = lane & 15;
  const int g = lane >> 4;

  // XCD-bijective swizzle: 2560 blocks, 8 XCDs, 320 per XCD (n fastest within)
  const int flat = blockIdx.x;
  const int tile = ((flat & 7) * 320) + (flat >> 3);
  const int m0 = (tile >> 2) * 128;
  const int n0 = (tile & 3) * 128;

  f32x4 acc[4][4] = {};

  int sr[4], sck[4];
#pragma unroll
  for (int o = 0; o < 4; ++o) {
    int ci = o * 256 + tid;
    sr[o] = ci >> 3;                    // dest row in tile
    sck[o] = (ci & 7) ^ (sr[o] & 7);    // logical chunk placed at this linear slot
  }

  for (int kt = 0; kt < 8; ++kt) {
    const int kb = kt * 64;
#pragma unroll
    for (int o = 0; o < 4; ++o) {
      int ci = o * 256 + tid;
      gll16(A + (size_t)(m0 + sr[o]) * 512 + kb + sck[o] * 8, As + ci * 8);
    }
#pragma unroll
    for (int o = 0; o < 4; ++o) {
      int ci = o * 256 + tid;
      gll16(Bt + (size_t)(n0 + sr[o]) * 512 + kb + sck[o] * 8, Bs + ci * 8);
    }
    __syncthreads();
#pragma unroll
    for (int kk = 0; kk < 2; ++kk) {
      bf16x8 af[4], bfr[4];
#pragma unroll
      for (int mf = 0; mf < 4; ++mf) {
        int r = wr * 64 + mf * 16 + u;
        int slot = (kk * 4 + g) ^ (r & 7);
        af[mf] = *(const bf16x8*)(As + r * 64 + slot * 8);
      }
#pragma unroll
      for (int nf = 0; nf < 4; ++nf) {
        int r = wc * 64 + nf * 16 + u;
        int slot = (kk * 4 + g) ^ (r & 7);
        bfr[nf] = *(const bf16x8*)(Bs + r * 64 + slot * 8);
      }
#pragma unroll
      for (int mf = 0; mf < 4; ++mf)
#pragma unroll
        for (int nf = 0; nf < 4; ++nf)
          acc[mf][nf] = __builtin_amdgcn_mfma_f32_16x16x32_bf16(af[mf], bfr[nf], acc[mf][nf], 0, 0, 0);
    }
    __syncthreads();
  }

#pragma unroll
  for (int nf = 0; nf < 4; ++nf) {
    const int col = n0 + wc * 64 + nf * 16 + u;
    const float bv = bias[col];
#pragma unroll
    for (int mf = 0; mf < 4; ++mf) {
      const int rbase = m0 + wr * 64 + mf * 16 + 4 * g;
#pragma unroll
      for (int j = 0; j < 4; ++j) {
        float v = acc[mf][nf][j] + bv;
        if constexpr (sizeof(OutT) == 2) {
          ((unsigned short*)C)[(size_t)(rbase + j) * 512 + col] = f2bf(v);
        } else {
          ((float*)C)[(size_t)(rbase + j) * 512 + col] = v;
        }
      }
    }
  }
}

// ---------------- tiny attention: per (b,h): 5x5 scores + softmax + PV ----------------
// wave handles 4 (b,h) pairs: lane = p*16 + u ; u covers hd in chunks of 4.
__global__ __launch_bounds__(256) void attn_s5(const unsigned short* __restrict__ qb,
                                               const unsigned short* __restrict__ kb,
                                               const unsigned short* __restrict__ vb,
                                               const float* __restrict__ pbias,
                                               unsigned short* __restrict__ ob) {
  __shared__ float sb[200];  // [H=8][5][5]
  if (threadIdx.x < 200) sb[threadIdx.x] = pbias[threadIdx.x];
  __syncthreads();

  const int lane = threadIdx.x & 63;
  const int p = lane >> 4, u = lane & 15;
  const int wv = blockIdx.x * (blockDim.x >> 6) + (threadIdx.x >> 6);
  const int nwv = gridDim.x * (blockDim.x >> 6);
  const int NPG = (16384 * 8) / 4;  // 32768 pair-groups

  for (int pg = wv; pg < NPG; pg += nwv) {
    const int idx = pg * 4 + p;
    const int b = idx >> 3, h = idx & 7;
    const size_t base = (size_t)(b * 5) * 512 + h * 64 + u * 4;

    float qf[5][4], kf[5][4], vf[5][4];
#pragma unroll
    for (int s = 0; s < 5; ++s) {
      ushort4 tq = *(const ushort4*)(qb + base + (size_t)s * 512);
      ushort4 tk = *(const ushort4*)(kb + base + (size_t)s * 512);
      ushort4 tv = *(const ushort4*)(vb + base + (size_t)s * 512);
      qf[s][0] = bf2f(tq.x); qf[s][1] = bf2f(tq.y); qf[s][2] = bf2f(tq.z); qf[s][3] = bf2f(tq.w);
      kf[s][0] = bf2f(tk.x); kf[s][1] = bf2f(tk.y); kf[s][2] = bf2f(tk.z); kf[s][3] = bf2f(tk.w);
      vf[s][0] = bf2f(tv.x); vf[s][1] = bf2f(tv.y); vf[s][2] = bf2f(tv.z); vf[s][3] = bf2f(tv.w);
    }

    float sc[5][5];
#pragma unroll
    for (int s = 0; s < 5; ++s)
#pragma unroll
      for (int t = 0; t < 5; ++t)
        sc[s][t] = qf[s][0] * kf[t][0] + qf[s][1] * kf[t][1] + qf[s][2] * kf[t][2] + qf[s][3] * kf[t][3];

    // reduce across the 16-lane group (all lanes end with full sums)
#pragma unroll
    for (int m = 1; m < 16; m <<= 1)
#pragma unroll
      for (int s = 0; s < 5; ++s)
#pragma unroll
        for (int t = 0; t < 5; ++t)
          sc[s][t] += __shfl_xor(sc[s][t], m, 64);

    const float* bh = &sb[h * 25];
#pragma unroll
    for (int s = 0; s < 5; ++s) {
      float r0 = sc[s][0] * 0.125f + bh[s * 5 + 0];
      float r1 = sc[s][1] * 0.125f + bh[s * 5 + 1];
      float r2 = sc[s][2] * 0.125f + bh[s * 5 + 2];
      float r3 = sc[s][3] * 0.125f + bh[s * 5 + 3];
      float r4 = sc[s][4] * 0.125f + bh[s * 5 + 4];
      float mx = fmaxf(fmaxf(fmaxf(r0, r1), fmaxf(r2, r3)), r4);
      float e0 = __expf(r0 - mx), e1 = __expf(r1 - mx), e2 = __expf(r2 - mx),
            e3 = __expf(r3 - mx), e4 = __expf(r4 - mx);
      float rd = 1.0f / (e0 + e1 + e2 + e3 + e4);
      ushort4 o;
      float o0, o1, o2, o3;
      o0 = (e0 * vf[0][0] + e1 * vf[1][0] + e2 * vf[2][0] + e3 * vf[3][0] + e4 * vf[4][0]) * rd;
      o1 = (e0 * vf[0][1] + e1 * vf[1][1] + e2 * vf[2][1] + e3 * vf[3][1] + e4 * vf[4][1]) * rd;
      o2 = (e0 * vf[0][2] + e1 * vf[1][2] + e2 * vf[2][2] + e3 * vf[3][2] + e4 * vf[4][2]) * rd;
      o3 = (e0 * vf[0][3] + e1 * vf[1][3] + e2 * vf[2][3] + e3 * vf[3][3] + e4 * vf[4][3]) * rd;
      o.x = f2bf(o0); o.y = f2bf(o1); o.z = f2bf(o2); o.w = f2bf(o3);
      *(ushort4*)(ob + base + (size_t)s * 512) = o;
    }
  }
}

extern "C" void kernel_launch(void* const* d_in, const int* in_sizes, int n_in,
                              void* d_out, int out_size, void* d_ws, size_t ws_size,
                              hipStream_t stream) {
  const float* x  = (const float*)d_in[0];
  const float* Wq = (const float*)d_in[1];
  const float* bq = (const float*)d_in[2];
  const float* Wk = (const float*)d_in[3];
  const float* bk = (const float*)d_in[4];
  const float* Wv = (const float*)d_in[5];
  const float* bv = (const float*)d_in[6];
  const float* Wo = (const float*)d_in[7];
  const float* bo = (const float*)d_in[8];
  const float* pb = (const float*)d_in[9];

  char* ws = (char*)d_ws;
  unsigned short* wt = (unsigned short*)ws;                    // 4 x 512*512 bf16
  unsigned short* xb = (unsigned short*)(ws + 2097152);        // x bf16, later attn_out
  unsigned short* qb = (unsigned short*)(ws + 85983232);
  unsigned short* kbuf = (unsigned short*)(ws + 169869312);
  unsigned short* vbuf = (unsigned short*)(ws + 253755392);

  cvt_f32_bf16<<<2048, 256, 0, stream>>>(x, xb, 5242880);

  dim3 tb(32, 32), tg(16, 16);
  wtrans<<<tg, tb, 0, stream>>>(Wq, wt + 0 * 262144);
  wtrans<<<tg, tb, 0, stream>>>(Wk, wt + 1 * 262144);
  wtrans<<<tg, tb, 0, stream>>>(Wv, wt + 2 * 262144);
  wtrans<<<tg, tb, 0, stream>>>(Wo, wt + 3 * 262144);

  gemm_bt<unsigned short><<<2560, 256, 0, stream>>>(xb, wt + 0 * 262144, bq, qb);
  gemm_bt<unsigned short><<<2560, 256, 0, stream>>>(xb, wt + 1 * 262144, bk, kbuf);
  gemm_bt<unsigned short><<<2560, 256, 0, stream>>>(xb, wt + 2 * 262144, bv, vbuf);

  attn_s5<<<2048, 256, 0, stream>>>(qb, kbuf, vbuf, pb, xb);

  gemm_bt<float><<<2560, 256, 0, stream>>>(xb, wt + 3 * 262144, bo, (float*)d_out);
}

// Round 2
// 646.123 us; speedup vs baseline: 1.0039x; 1.0039x over previous
//
#include <hip/hip_runtime.h>

typedef __attribute__((ext_vector_type(4))) float f32x4;
typedef __attribute__((ext_vector_type(8))) short bf16x8;
typedef __attribute__((ext_vector_type(8))) unsigned short u16x8;

__device__ __forceinline__ unsigned short f2bf(float f) {
  unsigned int u = __float_as_uint(f);
  u += 0x7FFFu + ((u >> 16) & 1u);
  return (unsigned short)(u >> 16);
}
__device__ __forceinline__ float bf2f(unsigned short s) {
  return __uint_as_float(((unsigned int)s) << 16);
}

__device__ __forceinline__ void gll16(const void* g, void* l) {
  __builtin_amdgcn_global_load_lds((const __attribute__((address_space(1))) void*)g,
                                   (__attribute__((address_space(3))) void*)l, 16, 0, 0);
}

// ---------------- x (fp32) -> bf16 ----------------
__global__ __launch_bounds__(256) void cvt_f32_bf16(const float* __restrict__ in,
                                                    unsigned short* __restrict__ out,
                                                    int n8) {
  int i = blockIdx.x * blockDim.x + threadIdx.x;
  int stride = gridDim.x * blockDim.x;
  for (; i < n8; i += stride) {
    const float4* p = (const float4*)in + (size_t)i * 2;
    float4 a = p[0], b = p[1];
    u16x8 r;
    r[0] = f2bf(a.x); r[1] = f2bf(a.y); r[2] = f2bf(a.z); r[3] = f2bf(a.w);
    r[4] = f2bf(b.x); r[5] = f2bf(b.y); r[6] = f2bf(b.z); r[7] = f2bf(b.w);
    *(u16x8*)(out + (size_t)i * 8) = r;
  }
}

// ---------------- W [K][N] fp32 -> Wt [N][K] bf16 ----------------
__global__ __launch_bounds__(1024) void wtrans(const float* __restrict__ W,
                                               unsigned short* __restrict__ Wt) {
  __shared__ float t[32][33];
  const int k0 = blockIdx.x * 32, n0 = blockIdx.y * 32;
  t[threadIdx.y][threadIdx.x] = W[(size_t)(k0 + threadIdx.y) * 512 + n0 + threadIdx.x];
  __syncthreads();
  Wt[(size_t)(n0 + threadIdx.y) * 512 + k0 + threadIdx.x] = f2bf(t[threadIdx.x][threadIdx.y]);
}

// ---------------- bias concat [bq|bk|bv] -> bcat[1536] ----------------
__global__ __launch_bounds__(256) void bcat_k(const float* __restrict__ bq,
                                              const float* __restrict__ bk,
                                              const float* __restrict__ bv,
                                              float* __restrict__ bc) {
  int i = blockIdx.x * 256 + threadIdx.x;
  if (i < 1536) {
    float v = (i < 512) ? bq[i] : (i < 1024 ? bk[i - 512] : bv[i - 1024]);
    bc[i] = v;
  }
}

// ---------------- 2-phase dbuf GEMM: C[M][Ncols] = A[M][512] * Bt^T (+bias) ----------------
// Bt stored [Ncols][512] bf16 row-major. 128x128 tile, BK=64, 4 waves (2x2),
// 16x16x32 MFMA. XOR-8 swizzle: linear gll16 dest + pre-swizzled global src (rule #21).
// T3-minimum 2-phase: STAGE(next) issued BEFORE compute(cur); one barrier per K-step.
template <typename OutT>
__global__ __launch_bounds__(256, 2) void gemm2p(const unsigned short* __restrict__ A,
                                                 const unsigned short* __restrict__ Bt,
                                                 const float* __restrict__ bias,
                                                 OutT* __restrict__ C,
                                                 int Ntl, int Ncols) {
  __shared__ unsigned short As[2][128 * 64];
  __shared__ unsigned short Bs[2][128 * 64];

  const int tid = threadIdx.x;
  const int lane = tid & 63;
  const int wid = tid >> 6;
  const int wr = wid >> 1, wc = wid & 1;
  const int u = lane & 15, g = lane >> 4;

  // XCD-bijective swizzle (grid divisible by 8)
  const int chunk = gridDim.x >> 3;
  const int flat = blockIdx.x;
  const int tile = (flat & 7) * chunk + (flat >> 3);
  const int mt = tile / Ntl, nt = tile - mt * Ntl;
  const int m0 = mt * 128, n0 = nt * 128;

  // per-thread staging descriptors (hoisted out of K-loop)
  const unsigned short* ap[4];
  const unsigned short* bp[4];
  int ldsoff[4];
#pragma unroll
  for (int o = 0; o < 4; ++o) {
    int c = o * 256 + tid;
    int r = c >> 3, s = (c & 7) ^ (r & 7);  // inverse placement (involution)
    ldsoff[o] = c * 8;
    ap[o] = A + (size_t)(m0 + r) * 512 + s * 8;
    bp[o] = Bt + (size_t)(n0 + r) * 512 + s * 8;
  }

  f32x4 acc[4][4] = {};

  auto STAGE = [&](int buf, int kb) {
#pragma unroll
    for (int o = 0; o < 4; ++o) gll16(ap[o] + kb, &As[buf][ldsoff[o]]);
#pragma unroll
    for (int o = 0; o < 4; ++o) gll16(bp[o] + kb, &Bs[buf][ldsoff[o]]);
  };
  auto COMPUTE = [&](int buf) {
#pragma unroll
    for (int kk = 0; kk < 2; ++kk) {
      bf16x8 af[4], bfr[4];
#pragma unroll
      for (int mf = 0; mf < 4; ++mf) {
        int r = wr * 64 + mf * 16 + u;
        int slot = (kk * 4 + g) ^ (r & 7);
        af[mf] = *(const bf16x8*)(&As[buf][r * 64 + slot * 8]);
      }
#pragma unroll
      for (int nf = 0; nf < 4; ++nf) {
        int r = wc * 64 + nf * 16 + u;
        int slot = (kk * 4 + g) ^ (r & 7);
        bfr[nf] = *(const bf16x8*)(&Bs[buf][r * 64 + slot * 8]);
      }
#pragma unroll
      for (int mf = 0; mf < 4; ++mf)
#pragma unroll
        for (int nf = 0; nf < 4; ++nf)
          acc[mf][nf] = __builtin_amdgcn_mfma_f32_16x16x32_bf16(af[mf], bfr[nf], acc[mf][nf], 0, 0, 0);
    }
  };

  STAGE(0, 0);
  __syncthreads();
#pragma unroll
  for (int kt = 0; kt < 7; ++kt) {
    STAGE((kt + 1) & 1, (kt + 1) * 64);  // issue next-tile loads first
    COMPUTE(kt & 1);                      // compute current from LDS
    __syncthreads();                      // drain (vmcnt 0) + reuse-protect
  }
  COMPUTE(1);

#pragma unroll
  for (int nf = 0; nf < 4; ++nf) {
    const int col = n0 + wc * 64 + nf * 16 + u;
    const float bv = bias[col];
#pragma unroll
    for (int mf = 0; mf < 4; ++mf) {
      const int rbase = m0 + wr * 64 + mf * 16 + 4 * g;
#pragma unroll
      for (int j = 0; j < 4; ++j) {
        float v = acc[mf][nf][j] + bv;
        if constexpr (sizeof(OutT) == 2) {
          ((unsigned short*)C)[(size_t)(rbase + j) * Ncols + col] = f2bf(v);
        } else {
          ((float*)C)[(size_t)(rbase + j) * Ncols + col] = v;
        }
      }
    }
  }
}

// ---------------- tiny attention on fused qkv[81920][1536] ----------------
// wave handles 4 (b,h) pairs: lane = p*16 + u ; u covers hd in chunks of 4.
__global__ __launch_bounds__(256) void attn_s5(const unsigned short* __restrict__ qkv,
                                               const float* __restrict__ pbias,
                                               unsigned short* __restrict__ ao) {
  __shared__ float sb[200];  // [H=8][5][5]
  if (threadIdx.x < 200) sb[threadIdx.x] = pbias[threadIdx.x];
  __syncthreads();

  const int lane = threadIdx.x & 63;
  const int p = lane >> 4, u = lane & 15;
  const int wv = blockIdx.x * (blockDim.x >> 6) + (threadIdx.x >> 6);
  const int nwv = gridDim.x * (blockDim.x >> 6);
  const int NPG = (16384 * 8) / 4;  // 32768 pair-groups

  for (int pg = wv; pg < NPG; pg += nwv) {
    const int idx = pg * 4 + p;
    const int b = idx >> 3, h = idx & 7;
    const size_t rbase = (size_t)(b * 5) * 1536 + h * 64 + u * 4;

    float qf[5][4], kf[5][4], vf[5][4];
#pragma unroll
    for (int s = 0; s < 5; ++s) {
      ushort4 tq = *(const ushort4*)(qkv + rbase + (size_t)s * 1536);
      ushort4 tk = *(const ushort4*)(qkv + rbase + (size_t)s * 1536 + 512);
      ushort4 tv = *(const ushort4*)(qkv + rbase + (size_t)s * 1536 + 1024);
      qf[s][0] = bf2f(tq.x); qf[s][1] = bf2f(tq.y); qf[s][2] = bf2f(tq.z); qf[s][3] = bf2f(tq.w);
      kf[s][0] = bf2f(tk.x); kf[s][1] = bf2f(tk.y); kf[s][2] = bf2f(tk.z); kf[s][3] = bf2f(tk.w);
      vf[s][0] = bf2f(tv.x); vf[s][1] = bf2f(tv.y); vf[s][2] = bf2f(tv.z); vf[s][3] = bf2f(tv.w);
    }

    float sc[5][5];
#pragma unroll
    for (int s = 0; s < 5; ++s)
#pragma unroll
      for (int t = 0; t < 5; ++t)
        sc[s][t] = qf[s][0] * kf[t][0] + qf[s][1] * kf[t][1] + qf[s][2] * kf[t][2] + qf[s][3] * kf[t][3];

#pragma unroll
    for (int m = 1; m < 16; m <<= 1)
#pragma unroll
      for (int s = 0; s < 5; ++s)
#pragma unroll
        for (int t = 0; t < 5; ++t)
          sc[s][t] += __shfl_xor(sc[s][t], m, 64);

    const float* bh = &sb[h * 25];
#pragma unroll
    for (int s = 0; s < 5; ++s) {
      float r0 = sc[s][0] * 0.125f + bh[s * 5 + 0];
      float r1 = sc[s][1] * 0.125f + bh[s * 5 + 1];
      float r2 = sc[s][2] * 0.125f + bh[s * 5 + 2];
      float r3 = sc[s][3] * 0.125f + bh[s * 5 + 3];
      float r4 = sc[s][4] * 0.125f + bh[s * 5 + 4];
      float mx = fmaxf(fmaxf(fmaxf(r0, r1), fmaxf(r2, r3)), r4);
      float e0 = __expf(r0 - mx), e1 = __expf(r1 - mx), e2 = __expf(r2 - mx),
            e3 = __expf(r3 - mx), e4 = __expf(r4 - mx);
      float rd = 1.0f / (e0 + e1 + e2 + e3 + e4);
      float o0 = (e0 * vf[0][0] + e1 * vf[1][0] + e2 * vf[2][0] + e3 * vf[3][0] + e4 * vf[4][0]) * rd;
      float o1 = (e0 * vf[0][1] + e1 * vf[1][1] + e2 * vf[2][1] + e3 * vf[3][1] + e4 * vf[4][1]) * rd;
      float o2 = (e0 * vf[0][2] + e1 * vf[1][2] + e2 * vf[2][2] + e3 * vf[3][2] + e4 * vf[4][2]) * rd;
      float o3 = (e0 * vf[0][3] + e1 * vf[1][3] + e2 * vf[2][3] + e3 * vf[3][3] + e4 * vf[4][3]) * rd;
      ushort4 o;
      o.x = f2bf(o0); o.y = f2bf(o1); o.z = f2bf(o2); o.w = f2bf(o3);
      *(ushort4*)(ao + (size_t)(b * 5 + s) * 512 + h * 64 + u * 4) = o;
    }
  }
}

extern "C" void kernel_launch(void* const* d_in, const int* in_sizes, int n_in,
                              void* d_out, int out_size, void* d_ws, size_t ws_size,
                              hipStream_t stream) {
  const float* x  = (const float*)d_in[0];
  const float* Wq = (const float*)d_in[1];
  const float* bq = (const float*)d_in[2];
  const float* Wk = (const float*)d_in[3];
  const float* bk = (const float*)d_in[4];
  const float* Wv = (const float*)d_in[5];
  const float* bv = (const float*)d_in[6];
  const float* Wo = (const float*)d_in[7];
  const float* bo = (const float*)d_in[8];
  const float* pb = (const float*)d_in[9];

  char* ws = (char*)d_ws;
  unsigned short* wt_all = (unsigned short*)ws;                      // [1536][512] bf16
  unsigned short* wtO    = (unsigned short*)(ws + 1572864);          // [512][512] bf16
  float*          bc     = (float*)(ws + 2097152);                   // [1536] f32
  unsigned short* xb     = (unsigned short*)(ws + 2103296);          // x bf16 (84MB), later attn_out
  unsigned short* qkv    = (unsigned short*)(ws + 85989376);         // [81920][1536] bf16 (252MB)

  cvt_f32_bf16<<<2048, 256, 0, stream>>>(x, xb, 5242880);

  dim3 tb(32, 32), tg(16, 16);
  wtrans<<<tg, tb, 0, stream>>>(Wq, wt_all + 0 * 262144);
  wtrans<<<tg, tb, 0, stream>>>(Wk, wt_all + 1 * 262144);
  wtrans<<<tg, tb, 0, stream>>>(Wv, wt_all + 2 * 262144);
  wtrans<<<tg, tb, 0, stream>>>(Wo, wtO);
  bcat_k<<<6, 256, 0, stream>>>(bq, bk, bv, bc);

  // fused QKV GEMM: M=81920, N=1536, K=512 -> 640 x 12 = 7680 tiles
  gemm2p<unsigned short><<<7680, 256, 0, stream>>>(xb, wt_all, bc, qkv, 12, 1536);

  attn_s5<<<2048, 256, 0, stream>>>(qkv, pb, xb);

  // output GEMM: M=81920, N=512 -> 640 x 4 = 2560 tiles, fp32 out
  gemm2p<float><<<2560, 256, 0, stream>>>(xb, wtO, bo, (float*)d_out, 4, 512);
}

// Round 3
// 621.344 us; speedup vs baseline: 1.0439x; 1.0399x over previous
//
#include <hip/hip_runtime.h>

typedef __attribute__((ext_vector_type(4))) float f32x4;
typedef __attribute__((ext_vector_type(8))) short bf16x8;
typedef __attribute__((ext_vector_type(8))) unsigned short u16x8;

__device__ __forceinline__ unsigned short f2bf(float f) {
  unsigned int u = __float_as_uint(f);
  u += 0x7FFFu + ((u >> 16) & 1u);
  return (unsigned short)(u >> 16);
}
__device__ __forceinline__ float bf2f(unsigned short s) {
  return __uint_as_float(((unsigned int)s) << 16);
}

__device__ __forceinline__ void gll16(const void* g, void* l) {
  __builtin_amdgcn_global_load_lds((const __attribute__((address_space(1))) void*)g,
                                   (__attribute__((address_space(3))) void*)l, 16, 0, 0);
}

// ---------------- x (fp32) -> bf16 ----------------
__global__ __launch_bounds__(256) void cvt_f32_bf16(const float* __restrict__ in,
                                                    unsigned short* __restrict__ out,
                                                    int n8) {
  int i = blockIdx.x * blockDim.x + threadIdx.x;
  int stride = gridDim.x * blockDim.x;
  for (; i < n8; i += stride) {
    const float4* p = (const float4*)in + (size_t)i * 2;
    float4 a = p[0], b = p[1];
    u16x8 r;
    r[0] = f2bf(a.x); r[1] = f2bf(a.y); r[2] = f2bf(a.z); r[3] = f2bf(a.w);
    r[4] = f2bf(b.x); r[5] = f2bf(b.y); r[6] = f2bf(b.z); r[7] = f2bf(b.w);
    *(u16x8*)(out + (size_t)i * 8) = r;
  }
}

// ---------------- W [K][N] fp32 -> Wt [N][K] bf16 ----------------
__global__ __launch_bounds__(1024) void wtrans(const float* __restrict__ W,
                                               unsigned short* __restrict__ Wt) {
  __shared__ float t[32][33];
  const int k0 = blockIdx.x * 32, n0 = blockIdx.y * 32;
  t[threadIdx.y][threadIdx.x] = W[(size_t)(k0 + threadIdx.y) * 512 + n0 + threadIdx.x];
  __syncthreads();
  Wt[(size_t)(n0 + threadIdx.y) * 512 + k0 + threadIdx.x] = f2bf(t[threadIdx.x][threadIdx.y]);
}

// ---------------- bias concat [bq|bk|bv] -> bcat[1536] ----------------
__global__ __launch_bounds__(256) void bcat_k(const float* __restrict__ bq,
                                              const float* __restrict__ bk,
                                              const float* __restrict__ bv,
                                              float* __restrict__ bc) {
  int i = blockIdx.x * 256 + threadIdx.x;
  if (i < 1536) {
    float v = (i < 512) ? bq[i] : (i < 1024 ? bk[i - 512] : bv[i - 1024]);
    bc[i] = v;
  }
}

// =====================================================================
// 256x256 8-phase GEMM (T2+T3+T4+T5): C[M][Ncols] = A[M][512] * Bt^T + bias
// Bt stored [Ncols][512] bf16. 512 thr = 8 waves (2M x 4N), BK=64, dbuf LDS
// 128KB. Wave m-frags interleaved at 16 rows: frag mf -> row (mf*2+wm)*16;
// n-frags: nf -> col (nf*4+wn)*16. So frag-half 0/1 == LDS chunk rows
// 0-127 / 128-255 for ALL waves (staging chunks = 64 rows, 1 gll16/thread).
// XOR-8 swizzle: linear gll16 dest + pre-swizzled global src; read XORs back.
// Counted vmcnt: never 0 in main loop (VMC(2) @p0, VMC(4) @p3).
// =====================================================================

#define BAR() __builtin_amdgcn_s_barrier()
#define LGKM0() do { asm volatile("s_waitcnt lgkmcnt(0)" ::: "memory"); \
                     __builtin_amdgcn_sched_barrier(0); } while (0)
#define VMC(n) asm volatile("s_waitcnt vmcnt(" #n ")" ::: "memory")

#define STG_A(buf, kb, ch) gll16(aBase + (size_t)(ch) * 64 * 512 + (kb), &As[buf][(ch) * 4096 + dstoff])
#define STG_B(buf, kb, ch) gll16(bBase + (size_t)(ch) * 64 * 512 + (kb), &Bs[buf][(ch) * 4096 + dstoff])

#define RD_A(buf, mh)                                                         \
  {                                                                           \
    _Pragma("unroll") for (int i = 0; i < 4; ++i) {                           \
      const int r_ = (((mh) * 4 + i) * 2 + wm) * 16 + u;                      \
      af[i][0] = *(const bf16x8*)&As[buf][r_ * 64 + aslot0];                  \
      af[i][1] = *(const bf16x8*)&As[buf][r_ * 64 + aslot1];                  \
    }                                                                         \
  }
#define RD_B(buf, nh)                                                         \
  {                                                                           \
    _Pragma("unroll") for (int j = 0; j < 2; ++j) {                           \
      const int r_ = (((nh) * 2 + j) * 4 + wn) * 16 + u;                      \
      bfr[j][0] = *(const bf16x8*)&Bs[buf][r_ * 64 + aslot0];                 \
      bfr[j][1] = *(const bf16x8*)&Bs[buf][r_ * 64 + aslot1];                 \
    }                                                                         \
  }
#define MM(mh, nh)                                                            \
  {                                                                           \
    _Pragma("unroll") for (int i = 0; i < 4; ++i)                             \
      _Pragma("unroll") for (int j = 0; j < 2; ++j)                           \
        _Pragma("unroll") for (int kk = 0; kk < 2; ++kk)                      \
          acc[(mh) * 4 + i][(nh) * 2 + j] = __builtin_amdgcn_mfma_f32_16x16x32_bf16( \
              af[i][kk], bfr[j][kk], acc[(mh) * 4 + i][(nh) * 2 + j], 0, 0, 0); \
  }

template <typename OutT>
__global__ __launch_bounds__(512, 2) void gemm8p(const unsigned short* __restrict__ A,
                                                 const unsigned short* __restrict__ Bt,
                                                 const float* __restrict__ bias,
                                                 OutT* __restrict__ C,
                                                 int Ntl, int Ncols) {
  __shared__ unsigned short As[2][256 * 64];
  __shared__ unsigned short Bs[2][256 * 64];

  const int tid = threadIdx.x;
  const int lane = tid & 63;
  const int wid = tid >> 6;
  const int wm = wid >> 2;   // 0..1
  const int wn = wid & 3;    // 0..3
  const int u = lane & 15, g = lane >> 4;

  // XCD-bijective block swizzle (grid % 8 == 0)
  const int chunkg = gridDim.x >> 3;
  const int tile = (blockIdx.x & 7) * chunkg + (blockIdx.x >> 3);
  const int mt = tile / Ntl, nt = tile - mt * Ntl;
  const int m0 = mt * 256, n0 = nt * 256;

  // staging: thread covers 16B unit: row tid>>3 within 64-row chunk, slot tid&7
  const int srow = tid >> 3;
  const int sswz = ((tid & 7) ^ (srow & 7)) * 8;  // pre-swizzled source k-offset
  const unsigned short* aBase = A + (size_t)(m0 + srow) * 512 + sswz;
  const unsigned short* bBase = Bt + (size_t)(n0 + srow) * 512 + sswz;
  const int dstoff = tid * 8;  // linear LDS dest (wave-uniform base + lane*16B)

  // fragment read slots (row&7 == u&7 since frag rows are multiples of 16 + u)
  const int aslot0 = ((0 + g) ^ (u & 7)) * 8;
  const int aslot1 = ((4 + g) ^ (u & 7)) * 8;

  f32x4 acc[8][4] = {};
  bf16x8 af[4][2], bfr[2][2];

  // ---- prologue: stage kt=0 fully into buf0 (order A01,B01,A23,B23) ----
  STG_A(0, 0, 0); STG_A(0, 0, 1); STG_B(0, 0, 0); STG_B(0, 0, 1);
  STG_A(0, 0, 2); STG_A(0, 0, 3); STG_B(0, 0, 2); STG_B(0, 0, 3);
  VMC(4);  // A01,B01 landed; A23,B23 in flight
  BAR();

  // ---- main loop: kt = 0..6 compute buf[kt&1], stage kt+1 into buf[~kt&1] ----
  for (int kt = 0; kt < 7; ++kt) {
    const int cb = kt & 1, nb = cb ^ 1;
    const int kb = (kt + 1) * 64;
    // phase 0: Q(0,0)
    RD_A(cb, 0); RD_B(cb, 0);
    STG_A(nb, kb, 0); STG_A(nb, kb, 1);
    BAR(); LGKM0();
    __builtin_amdgcn_s_setprio(1); MM(0, 0); __builtin_amdgcn_s_setprio(0);
    VMC(2);  // drains cb's A23,B23 (issued last iter); nb's A01 stays in flight
    BAR();
    // phase 1: Q(0,1)
    RD_B(cb, 1);
    STG_B(nb, kb, 0); STG_B(nb, kb, 1);
    BAR(); LGKM0();
    __builtin_amdgcn_s_setprio(1); MM(0, 1); __builtin_amdgcn_s_setprio(0);
    BAR();
    // phase 2: Q(1,0)
    RD_A(cb, 1); RD_B(cb, 0);
    STG_A(nb, kb, 2); STG_A(nb, kb, 3);
    BAR(); LGKM0();
    __builtin_amdgcn_s_setprio(1); MM(1, 0); __builtin_amdgcn_s_setprio(0);
    BAR();
    // phase 3: Q(1,1)
    RD_B(cb, 1);
    STG_B(nb, kb, 2); STG_B(nb, kb, 3);
    BAR(); LGKM0();
    __builtin_amdgcn_s_setprio(1); MM(1, 1); __builtin_amdgcn_s_setprio(0);
    VMC(4);  // nb's A01,B01 landed for next iter's phase 0
    BAR();
  }

  // ---- final K-tile (kt=7, buf1), no staging ----
  RD_A(1, 0); RD_B(1, 0);
  BAR(); LGKM0();
  __builtin_amdgcn_s_setprio(1); MM(0, 0); __builtin_amdgcn_s_setprio(0);
  VMC(0); BAR();
  RD_B(1, 1);
  BAR(); LGKM0();
  __builtin_amdgcn_s_setprio(1); MM(0, 1); __builtin_amdgcn_s_setprio(0);
  BAR();
  RD_A(1, 1); RD_B(1, 0);
  BAR(); LGKM0();
  __builtin_amdgcn_s_setprio(1); MM(1, 0); __builtin_amdgcn_s_setprio(0);
  BAR();
  RD_B(1, 1);
  LGKM0();
  __builtin_amdgcn_s_setprio(1); MM(1, 1); __builtin_amdgcn_s_setprio(0);

  // ---- epilogue ----
#pragma unroll
  for (int nf = 0; nf < 4; ++nf) {
    const int col = n0 + (nf * 4 + wn) * 16 + u;
    const float bv = bias[col];
#pragma unroll
    for (int mf = 0; mf < 8; ++mf) {
      const int rbase = m0 + (mf * 2 + wm) * 16 + 4 * g;
#pragma unroll
      for (int j = 0; j < 4; ++j) {
        float v = acc[mf][nf][j] + bv;
        if constexpr (sizeof(OutT) == 2) {
          ((unsigned short*)C)[(size_t)(rbase + j) * Ncols + col] = f2bf(v);
        } else {
          ((float*)C)[(size_t)(rbase + j) * Ncols + col] = v;
        }
      }
    }
  }
}

// ---------------- tiny attention on fused qkv[81920][1536] ----------------
__global__ __launch_bounds__(256) void attn_s5(const unsigned short* __restrict__ qkv,
                                               const float* __restrict__ pbias,
                                               unsigned short* __restrict__ ao) {
  __shared__ float sb[200];  // [H=8][5][5]
  if (threadIdx.x < 200) sb[threadIdx.x] = pbias[threadIdx.x];
  __syncthreads();

  const int lane = threadIdx.x & 63;
  const int p = lane >> 4, u = lane & 15;
  const int wv = blockIdx.x * (blockDim.x >> 6) + (threadIdx.x >> 6);
  const int nwv = gridDim.x * (blockDim.x >> 6);
  const int NPG = (16384 * 8) / 4;  // 32768 pair-groups

  for (int pg = wv; pg < NPG; pg += nwv) {
    const int idx = pg * 4 + p;
    const int b = idx >> 3, h = idx & 7;
    const size_t rbase = (size_t)(b * 5) * 1536 + h * 64 + u * 4;

    float qf[5][4], kf[5][4], vf[5][4];
#pragma unroll
    for (int s = 0; s < 5; ++s) {
      ushort4 tq = *(const ushort4*)(qkv + rbase + (size_t)s * 1536);
      ushort4 tk = *(const ushort4*)(qkv + rbase + (size_t)s * 1536 + 512);
      ushort4 tv = *(const ushort4*)(qkv + rbase + (size_t)s * 1536 + 1024);
      qf[s][0] = bf2f(tq.x); qf[s][1] = bf2f(tq.y); qf[s][2] = bf2f(tq.z); qf[s][3] = bf2f(tq.w);
      kf[s][0] = bf2f(tk.x); kf[s][1] = bf2f(tk.y); kf[s][2] = bf2f(tk.z); kf[s][3] = bf2f(tk.w);
      vf[s][0] = bf2f(tv.x); vf[s][1] = bf2f(tv.y); vf[s][2] = bf2f(tv.z); vf[s][3] = bf2f(tv.w);
    }

    float sc[5][5];
#pragma unroll
    for (int s = 0; s < 5; ++s)
#pragma unroll
      for (int t = 0; t < 5; ++t)
        sc[s][t] = qf[s][0] * kf[t][0] + qf[s][1] * kf[t][1] + qf[s][2] * kf[t][2] + qf[s][3] * kf[t][3];

#pragma unroll
    for (int m = 1; m < 16; m <<= 1)
#pragma unroll
      for (int s = 0; s < 5; ++s)
#pragma unroll
        for (int t = 0; t < 5; ++t)
          sc[s][t] += __shfl_xor(sc[s][t], m, 64);

    const float* bh = &sb[h * 25];
#pragma unroll
    for (int s = 0; s < 5; ++s) {
      float r0 = sc[s][0] * 0.125f + bh[s * 5 + 0];
      float r1 = sc[s][1] * 0.125f + bh[s * 5 + 1];
      float r2 = sc[s][2] * 0.125f + bh[s * 5 + 2];
      float r3 = sc[s][3] * 0.125f + bh[s * 5 + 3];
      float r4 = sc[s][4] * 0.125f + bh[s * 5 + 4];
      float mx = fmaxf(fmaxf(fmaxf(r0, r1), fmaxf(r2, r3)), r4);
      float e0 = __expf(r0 - mx), e1 = __expf(r1 - mx), e2 = __expf(r2 - mx),
            e3 = __expf(r3 - mx), e4 = __expf(r4 - mx);
      float rd = 1.0f / (e0 + e1 + e2 + e3 + e4);
      float o0 = (e0 * vf[0][0] + e1 * vf[1][0] + e2 * vf[2][0] + e3 * vf[3][0] + e4 * vf[4][0]) * rd;
      float o1 = (e0 * vf[0][1] + e1 * vf[1][1] + e2 * vf[2][1] + e3 * vf[3][1] + e4 * vf[4][1]) * rd;
      float o2 = (e0 * vf[0][2] + e1 * vf[1][2] + e2 * vf[2][2] + e3 * vf[3][2] + e4 * vf[4][2]) * rd;
      float o3 = (e0 * vf[0][3] + e1 * vf[1][3] + e2 * vf[2][3] + e3 * vf[3][3] + e4 * vf[4][3]) * rd;
      ushort4 o;
      o.x = f2bf(o0); o.y = f2bf(o1); o.z = f2bf(o2); o.w = f2bf(o3);
      *(ushort4*)(ao + (size_t)(b * 5 + s) * 512 + h * 64 + u * 4) = o;
    }
  }
}

extern "C" void kernel_launch(void* const* d_in, const int* in_sizes, int n_in,
                              void* d_out, int out_size, void* d_ws, size_t ws_size,
                              hipStream_t stream) {
  const float* x  = (const float*)d_in[0];
  const float* Wq = (const float*)d_in[1];
  const float* bq = (const float*)d_in[2];
  const float* Wk = (const float*)d_in[3];
  const float* bk = (const float*)d_in[4];
  const float* Wv = (const float*)d_in[5];
  const float* bv = (const float*)d_in[6];
  const float* Wo = (const float*)d_in[7];
  const float* bo = (const float*)d_in[8];
  const float* pb = (const float*)d_in[9];

  char* ws = (char*)d_ws;
  unsigned short* wt_all = (unsigned short*)ws;                      // [1536][512] bf16
  unsigned short* wtO    = (unsigned short*)(ws + 1572864);          // [512][512] bf16
  float*          bc     = (float*)(ws + 2097152);                   // [1536] f32
  unsigned short* xb     = (unsigned short*)(ws + 2103296);          // x bf16 (84MB), later attn_out
  unsigned short* qkv    = (unsigned short*)(ws + 85989376);         // [81920][1536] bf16 (252MB)

  cvt_f32_bf16<<<2048, 256, 0, stream>>>(x, xb, 5242880);

  dim3 tb(32, 32), tg(16, 16);
  wtrans<<<tg, tb, 0, stream>>>(Wq, wt_all + 0 * 262144);
  wtrans<<<tg, tb, 0, stream>>>(Wk, wt_all + 1 * 262144);
  wtrans<<<tg, tb, 0, stream>>>(Wv, wt_all + 2 * 262144);
  wtrans<<<tg, tb, 0, stream>>>(Wo, wtO);
  bcat_k<<<6, 256, 0, stream>>>(bq, bk, bv, bc);

  // fused QKV GEMM: M=81920, N=1536 -> 320 x 6 = 1920 tiles of 256^2
  gemm8p<unsigned short><<<1920, 512, 0, stream>>>(xb, wt_all, bc, qkv, 6, 1536);

  attn_s5<<<2048, 256, 0, stream>>>(qkv, pb, xb);

  // output GEMM: M=81920, N=512 -> 320 x 2 = 640 tiles, fp32 out
  gemm8p<float><<<640, 512, 0, stream>>>(xb, wtO, bo, (float*)d_out, 2, 512);
}